// Round 8
// baseline (248.434 us; speedup 1.0000x reference)
//
#include <hip/hip_runtime.h>
#include <hip/hip_bf16.h>

#define NQ 6

typedef __attribute__((ext_vector_type(8))) short short8;
typedef __attribute__((ext_vector_type(4))) float floatx4;

// ---------------- ws layout (bytes) ----------------
// U_circ : float2[64*64]        @ 0        (32768 B)
// Mq     : float[18]            @ 32768
// cq     : float[3]             @ 32840
// W1bf   : short[64*2048]       @ 36864    (262144 B)
// qpart  : float[B*3]           @ 301056
#define WS_MQ_F   8192        // float offset of Mq
#define WS_CQ_F   (8192+18)
#define WS_W1BF_B 36864
#define WS_QPART_B 301056

// ============ K0: prep — U_circ columns, Mq/cq, W1->bf16 ============
__global__ __launch_bounds__(64) void prep_kernel(
    const float* __restrict__ qw, int n_layers,
    const float* __restrict__ W1, const float* __restrict__ Wq,
    const float* __restrict__ bq, const float* __restrict__ Wf,
    const float* __restrict__ bf, float* __restrict__ ws_f,
    short* __restrict__ w1bf)
{
    const int blk  = blockIdx.x;
    const int lane = threadIdx.x;

    if (blk == 0) {
        if (lane < 18) {
            int j = lane / 6, wi = lane % 6;
            float s = 0.f;
            for (int m = 0; m < 16; ++m) s += Wf[j*80 + 64 + m] * Wq[m*6 + wi];
            ws_f[WS_MQ_F + lane] = s;
        } else if (lane < 21) {
            int j = lane - 18;
            float s = bf[j];
            for (int m = 0; m < 16; ++m) s += Wf[j*80 + 64 + m] * bq[m];
            ws_f[WS_CQ_F + j] = s;
        }
    } else if (blk <= 64) {
        // U_circ column j: amplitudes-in-lanes, one wave
        const int j = blk - 1;
        float re = (lane == j) ? 1.f : 0.f;
        float im = 0.f;
        for (int l = 0; l < n_layers; ++l) {
            for (int w = 0; w < NQ; ++w) {
                const float* g = qw + (l*NQ + w)*3;
                float phi = g[0], th = g[1], om = g[2];
                float c, s;  __sincosf(0.5f*th, &s, &c);
                float sa, ca; __sincosf(0.5f*(phi+om), &sa, &ca);
                float sb, cb; __sincosf(0.5f*(phi-om), &sb, &cb);
                float u00r =  c*ca, u00i = -c*sa;
                float u01r = -s*cb, u01i = -s*sb;
                float u10r =  s*cb, u10i = -s*sb;
                float u11r =  c*ca, u11i =  c*sa;
                int p = 5 - w, mask = 1 << p;
                float pre = __shfl_xor(re, mask, 64);
                float pim = __shfl_xor(im, mask, 64);
                int b = (lane >> p) & 1;
                float mr = b ? u11r : u00r, mi = b ? u11i : u00i;
                float pr = b ? u10r : u01r, pi = b ? u10i : u01i;
                float nre = mr*re - mi*im + pr*pre - pi*pim;
                float nim = mr*im + mi*re + pr*pim + pi*pre;
                re = nre; im = nim;
            }
            int r = l % (NQ-1) + 1;
            for (int w = 0; w < NQ; ++w) {
                int tgt = (w + r) % NQ;
                int tmask = 1 << (5 - tgt);
                float pre = __shfl_xor(re, tmask, 64);
                float pim = __shfl_xor(im, tmask, 64);
                int cs = (lane >> (5 - w)) & 1;
                re = cs ? pre : re;
                im = cs ? pim : im;
            }
        }
        ws_f[(lane*64 + j)*2 + 0] = re;   // U[i=lane][j].re
        ws_f[(lane*64 + j)*2 + 1] = im;
    } else {
        // W1 fp32 -> bf16 (row-major [n][k]), blocks 65..320
        int idx = (blk - 65)*512 + lane*8;
        if (idx < 64*2048) {
            float4 a0 = *(const float4*)(W1 + idx);
            float4 a1 = *(const float4*)(W1 + idx + 4);
            union { short8 v; __hip_bfloat162 h[4]; } u;
            float2 f;
            f.x=a0.x; f.y=a0.y; u.h[0] = __float22bfloat162_rn(f);
            f.x=a0.z; f.y=a0.w; u.h[1] = __float22bfloat162_rn(f);
            f.x=a1.x; f.y=a1.y; u.h[2] = __float22bfloat162_rn(f);
            f.x=a1.z; f.y=a1.w; u.h[3] = __float22bfloat162_rn(f);
            *(short8*)(w1bf + idx) = u.v;
        }
    }
}

__device__ __forceinline__ short8 cvt_bf16x8(float4 a0, float4 a1) {
    union { short8 v; __hip_bfloat162 h[4]; } u;
    float2 f;
    f.x=a0.x; f.y=a0.y; u.h[0] = __float22bfloat162_rn(f);
    f.x=a0.z; f.y=a0.w; u.h[1] = __float22bfloat162_rn(f);
    f.x=a1.x; f.y=a1.y; u.h[2] = __float22bfloat162_rn(f);
    f.x=a1.z; f.y=a1.w; u.h[3] = __float22bfloat162_rn(f);
    return u.v;
}

// ============ K1: qpart[b][0..2] = Mq @ z(b) + cq ============
// 256 blocks x 256 threads; wave t evaluates U-rows [t*16,+16) for the
// block's 64 batch elements (lane = batch). Factored product state.
__global__ __launch_bounds__(256) void qpart_kernel(
    const float* __restrict__ xq, const float2* __restrict__ U,
    const float* __restrict__ ws_f, float* __restrict__ qpart)
{
    const int lane = threadIdx.x & 63;
    const int t = __builtin_amdgcn_readfirstlane((int)(threadIdx.x >> 6)); // 0..3
    const int b = blockIdx.x*64 + lane;

    __shared__ float zbuf[4][64][6];

    const float* x = xq + (size_t)b*6;
    float ah[8], al[8];
    ah[0] = 1.f;
    #pragma unroll
    for (int q = 0; q < 3; ++q) {
        float c, s; __sincosf(0.5f*x[q], &s, &c);
        const int sz = 1 << q;
        #pragma unroll
        for (int m = sz-1; m >= 0; --m) {
            float v = ah[m];
            ah[2*m+1] = v*s;
            ah[2*m+0] = v*c;
        }
    }
    al[0] = 1.f;
    #pragma unroll
    for (int q = 0; q < 3; ++q) {
        float c, s; __sincosf(0.5f*x[3+q], &s, &c);
        const int sz = 1 << q;
        #pragma unroll
        for (int m = sz-1; m >= 0; --m) {
            float v = al[m];
            al[2*m+1] = v*s;
            al[2*m+0] = v*c;
        }
    }

    float zp[6] = {0,0,0,0,0,0};
    const float2* Urow = U + t*16*64;   // wave-uniform -> scalar loads
    for (int ii = 0; ii < 16; ++ii) {
        float rr = 0.f, ri = 0.f;
        #pragma unroll
        for (int jh = 0; jh < 8; ++jh) {
            float sr = 0.f, si = 0.f;
            #pragma unroll
            for (int jl = 0; jl < 8; ++jl) {
                float2 u = Urow[ii*64 + jh*8 + jl];
                sr += u.x * al[jl];
                si += u.y * al[jl];
            }
            rr += ah[jh] * sr;
            ri += ah[jh] * si;
        }
        float p = rr*rr + ri*ri;
        int i = t*16 + ii;
        #pragma unroll
        for (int w = 0; w < 6; ++w) zp[w] += ((i >> (5-w)) & 1) ? -p : p;
    }
    #pragma unroll
    for (int w = 0; w < 6; ++w) zbuf[t][lane][w] = zp[w];
    __syncthreads();
    if (t == 0) {
        float z[6];
        #pragma unroll
        for (int w = 0; w < 6; ++w)
            z[w] = zbuf[0][lane][w] + zbuf[1][lane][w] + zbuf[2][lane][w] + zbuf[3][lane][w];
        #pragma unroll
        for (int j = 0; j < 3; ++j) {
            float v = ws_f[WS_CQ_F + j];
            #pragma unroll
            for (int w = 0; w < 6; ++w) v += ws_f[WS_MQ_F + j*6 + w] * z[w];
            qpart[(size_t)b*3 + j] = v;
        }
    }
}

// ============ K2: barrier-free streaming GEMM + ReLU + head ============
// 1024 blocks x 256 threads (4 waves) = 4 blocks/CU, 16 waves/CU.
// Block = 16 rows; wave t = K-quarter [t*512,+512), 16 k-steps, reg-direct
// loads, depth-1 prefetch, NO barriers in the loop. LDS reduce of the 4
// K-partials, then bias+ReLU+Wf head + qpart.
__global__ __launch_bounds__(256, 4) void gemm_kernel(
    const float* __restrict__ xc, const short* __restrict__ w1bf,
    const float* __restrict__ b1, const float* __restrict__ Wf,
    const float* __restrict__ qpart, float* __restrict__ out)
{
    const int tid  = threadIdx.x;
    const int lane = tid & 63;
    const int t    = __builtin_amdgcn_readfirstlane((int)(tid >> 6)); // 0..3
    const int blk  = blockIdx.x;
    const int rb   = blk * 16;

    __shared__ float accbuf[4][64][20];   // [wave][lane][16 used, pad->20]
    __shared__ float cl[16][65];

    const int a_l = lane >> 4;            // k-group 0..3
    const int m16 = lane & 15;            // row-in-tile / col-in-frag

    const float* ap = xc + (size_t)(rb + m16)*2048 + t*512 + a_l*8;
    const short* bp = w1bf + m16*2048 + t*512 + a_l*8;

    floatx4 acc0 = {0,0,0,0}, acc1 = {0,0,0,0}, acc2 = {0,0,0,0}, acc3 = {0,0,0,0};

    // prologue (k-step 0)
    float4 a0  = *(const float4*)ap;
    float4 a1  = *(const float4*)(ap + 4);
    short8 b0  = *(const short8*)(bp);
    short8 bv1 = *(const short8*)(bp + 16*2048);
    short8 b2  = *(const short8*)(bp + 32*2048);
    short8 b3  = *(const short8*)(bp + 48*2048);

    #pragma unroll
    for (int s = 1; s < 16; ++s) {
        const float* apn = ap + s*32;
        const short* bpn = bp + s*32;
        float4 na0 = *(const float4*)apn;
        float4 na1 = *(const float4*)(apn + 4);
        short8 nb0 = *(const short8*)(bpn);
        short8 nb1 = *(const short8*)(bpn + 16*2048);
        short8 nb2 = *(const short8*)(bpn + 32*2048);
        short8 nb3 = *(const short8*)(bpn + 48*2048);

        short8 av = cvt_bf16x8(a0, a1);
        acc0 = __builtin_amdgcn_mfma_f32_16x16x32_bf16(av, b0,  acc0, 0, 0, 0);
        acc1 = __builtin_amdgcn_mfma_f32_16x16x32_bf16(av, bv1, acc1, 0, 0, 0);
        acc2 = __builtin_amdgcn_mfma_f32_16x16x32_bf16(av, b2,  acc2, 0, 0, 0);
        acc3 = __builtin_amdgcn_mfma_f32_16x16x32_bf16(av, b3,  acc3, 0, 0, 0);

        a0 = na0; a1 = na1; b0 = nb0; bv1 = nb1; b2 = nb2; b3 = nb3;
    }
    {   // tail
        short8 av = cvt_bf16x8(a0, a1);
        acc0 = __builtin_amdgcn_mfma_f32_16x16x32_bf16(av, b0,  acc0, 0, 0, 0);
        acc1 = __builtin_amdgcn_mfma_f32_16x16x32_bf16(av, bv1, acc1, 0, 0, 0);
        acc2 = __builtin_amdgcn_mfma_f32_16x16x32_bf16(av, b2,  acc2, 0, 0, 0);
        acc3 = __builtin_amdgcn_mfma_f32_16x16x32_bf16(av, b3,  acc3, 0, 0, 0);
    }

    // store partials: frag layout n-col = lane&15 (+16c), m-row = a_l*4 + r
    #pragma unroll
    for (int r = 0; r < 4; ++r) {
        accbuf[t][lane][ 0 + r] = acc0[r];
        accbuf[t][lane][ 4 + r] = acc1[r];
        accbuf[t][lane][ 8 + r] = acc2[r];
        accbuf[t][lane][12 + r] = acc3[r];
    }
    __syncthreads();

    // reduce 4 K-partials: thread -> 4 cells (m = tid&15, n = (tid>>4)*4 + q)
    {
        const int m  = tid & 15;
        const int nb4 = tid >> 4;          // 0..15
        #pragma unroll
        for (int q = 0; q < 4; ++q) {
            const int n = nb4*4 + q;
            const int lsrc = (m >> 2)*16 + (n & 15);
            const int reg  = (n >> 4)*4 + (m & 3);
            float v = accbuf[0][lsrc][reg] + accbuf[1][lsrc][reg]
                    + accbuf[2][lsrc][reg] + accbuf[3][lsrc][reg];
            cl[m][n] = fmaxf(v + b1[n], 0.f);
        }
    }
    __syncthreads();

    // head: 48 threads: j = tid>>4 (0..2), m = tid&15
    if (tid < 48) {
        const int j = tid >> 4;
        const int m = tid & 15;
        float v = 0.f;
        #pragma unroll
        for (int col = 0; col < 64; ++col) v += Wf[j*80 + col] * cl[m][col];
        const int g = rb + m;
        out[(size_t)g*3 + j] = v + qpart[(size_t)g*3 + j];
    }
}

extern "C" void kernel_launch(void* const* d_in, const int* in_sizes, int n_in,
                              void* d_out, int out_size, void* d_ws, size_t ws_size,
                              hipStream_t stream) {
    const float* xc = (const float*)d_in[0];
    const float* xq = (const float*)d_in[1];
    const float* W1 = (const float*)d_in[2];
    const float* b1 = (const float*)d_in[3];
    const float* qw = (const float*)d_in[4];
    const float* Wq = (const float*)d_in[5];
    const float* bq = (const float*)d_in[6];
    const float* Wf = (const float*)d_in[7];
    const float* bf = (const float*)d_in[8];
    float* out = (float*)d_out;

    const int B = in_sizes[1] / NQ;                 // 16384
    const int n_layers = in_sizes[4] / (NQ * 3);    // 3

    char* ws = (char*)d_ws;
    float*  ws_f  = (float*)ws;
    float2* U     = (float2*)ws;
    short*  w1bf  = (short*)(ws + WS_W1BF_B);
    float*  qpart = (float*)(ws + WS_QPART_B);

    prep_kernel<<<dim3(321), dim3(64), 0, stream>>>(qw, n_layers, W1, Wq, bq, Wf, bf, ws_f, w1bf);
    qpart_kernel<<<dim3(B/64), dim3(256), 0, stream>>>(xq, U, ws_f, qpart);
    gemm_kernel<<<dim3(B/16), dim3(256), 0, stream>>>(xc, w1bf, b1, Wf, qpart, out);
}

// Round 10
// 237.556 us; speedup vs baseline: 1.0458x; 1.0458x over previous
//
#include <hip/hip_runtime.h>
#include <hip/hip_bf16.h>

#define NQ 6

typedef __attribute__((ext_vector_type(8))) short short8;
typedef __attribute__((ext_vector_type(4))) float floatx4;

// ---------------- ws layout (bytes) ----------------
// U_circ : float2[64*64]        @ 0        (32768 B)
// Mq     : float[18]            @ 32768
// cq     : float[3]             @ 32840
// W1bf   : short[64*2048]       @ 36864    (262144 B)
#define WS_MQ_F   8192        // float offset of Mq
#define WS_CQ_F   (8192+18)
#define WS_W1BF_B 36864

typedef const __attribute__((address_space(1))) void gvoid_t;
typedef __attribute__((address_space(3))) void lvoid_t;

// ============ K0: prep — U_circ columns, Mq/cq, W1->bf16 ============
__global__ __launch_bounds__(64) void prep_kernel(
    const float* __restrict__ qw, int n_layers,
    const float* __restrict__ W1, const float* __restrict__ Wq,
    const float* __restrict__ bq, const float* __restrict__ Wf,
    const float* __restrict__ bf, float* __restrict__ ws_f,
    short* __restrict__ w1bf)
{
    const int blk  = blockIdx.x;
    const int lane = threadIdx.x;

    if (blk == 0) {
        if (lane < 18) {
            int j = lane / 6, wi = lane % 6;
            float s = 0.f;
            for (int m = 0; m < 16; ++m) s += Wf[j*80 + 64 + m] * Wq[m*6 + wi];
            ws_f[WS_MQ_F + lane] = s;
        } else if (lane < 21) {
            int j = lane - 18;
            float s = bf[j];
            for (int m = 0; m < 16; ++m) s += Wf[j*80 + 64 + m] * bq[m];
            ws_f[WS_CQ_F + j] = s;
        }
    } else if (blk <= 64) {
        // U_circ column j: amplitudes-in-lanes, one wave
        const int j = blk - 1;
        float re = (lane == j) ? 1.f : 0.f;
        float im = 0.f;
        for (int l = 0; l < n_layers; ++l) {
            for (int w = 0; w < NQ; ++w) {
                const float* g = qw + (l*NQ + w)*3;
                float phi = g[0], th = g[1], om = g[2];
                float c, s;  __sincosf(0.5f*th, &s, &c);
                float sa, ca; __sincosf(0.5f*(phi+om), &sa, &ca);
                float sb, cb; __sincosf(0.5f*(phi-om), &sb, &cb);
                float u00r =  c*ca, u00i = -c*sa;
                float u01r = -s*cb, u01i = -s*sb;
                float u10r =  s*cb, u10i = -s*sb;
                float u11r =  c*ca, u11i =  c*sa;
                int p = 5 - w, mask = 1 << p;
                float pre = __shfl_xor(re, mask, 64);
                float pim = __shfl_xor(im, mask, 64);
                int b = (lane >> p) & 1;
                float mr = b ? u11r : u00r, mi = b ? u11i : u00i;
                float pr = b ? u10r : u01r, pi = b ? u10i : u01i;
                float nre = mr*re - mi*im + pr*pre - pi*pim;
                float nim = mr*im + mi*re + pr*pim + pi*pre;
                re = nre; im = nim;
            }
            int r = l % (NQ-1) + 1;
            for (int w = 0; w < NQ; ++w) {
                int tgt = (w + r) % NQ;
                int tmask = 1 << (5 - tgt);
                float pre = __shfl_xor(re, tmask, 64);
                float pim = __shfl_xor(im, tmask, 64);
                int cs = (lane >> (5 - w)) & 1;
                re = cs ? pre : re;
                im = cs ? pim : im;
            }
        }
        ws_f[(lane*64 + j)*2 + 0] = re;   // U[i=lane][j].re
        ws_f[(lane*64 + j)*2 + 1] = im;
    } else {
        // W1 fp32 -> bf16 (row-major [n][k]), blocks 65..320
        int idx = (blk - 65)*512 + lane*8;
        if (idx < 64*2048) {
            float4 a0 = *(const float4*)(W1 + idx);
            float4 a1 = *(const float4*)(W1 + idx + 4);
            union { short8 v; __hip_bfloat162 h[4]; } u;
            float2 f;
            f.x=a0.x; f.y=a0.y; u.h[0] = __float22bfloat162_rn(f);
            f.x=a0.z; f.y=a0.w; u.h[1] = __float22bfloat162_rn(f);
            f.x=a1.x; f.y=a1.y; u.h[2] = __float22bfloat162_rn(f);
            f.x=a1.z; f.y=a1.w; u.h[3] = __float22bfloat162_rn(f);
            *(short8*)(w1bf + idx) = u.v;
        }
    }
}

__device__ __forceinline__ short8 cvt_bf16x8(float4 a0, float4 a1) {
    union { short8 v; __hip_bfloat162 h[4]; } u;
    float2 f;
    f.x=a0.x; f.y=a0.y; u.h[0] = __float22bfloat162_rn(f);
    f.x=a0.z; f.y=a0.w; u.h[1] = __float22bfloat162_rn(f);
    f.x=a1.x; f.y=a1.y; u.h[2] = __float22bfloat162_rn(f);
    f.x=a1.z; f.y=a1.w; u.h[3] = __float22bfloat162_rn(f);
    return u.v;
}

// ============ K1: fused quantum + GEMM + ReLU + 3-wide head ============
// 512 blocks x 512 threads (8 waves, 32 rows, 2 blocks/CU). K = 32 chunks
// of 64. A: raw-fp32 global_load_lds DMA (zero stage regs/VALU), 3-slot
// ring, issued 2 chunks ahead; read-side fp32->bf16 cvt. B: bf16 DMA,
// 3-slot ring. Counted vmcnt(2) split barriers. Swizzle via pre-swizzled
// per-lane DMA source (linear LDS dest, m173 pattern).
__global__ __launch_bounds__(512, 4) void fused_kernel(
    const float* __restrict__ xq, const float2* __restrict__ U,
    const float* __restrict__ ws_f,
    const float* __restrict__ xc, const short* __restrict__ w1bf,
    const float* __restrict__ b1, const float* __restrict__ Wf,
    float* __restrict__ out)
{
    const int tid  = threadIdx.x;
    const int lane = tid & 63;
    const int t    = __builtin_amdgcn_readfirstlane((int)(tid >> 6)); // wave 0..7
    const int blk  = blockIdx.x;

    __shared__ __align__(16) char Aring[3*8192];   // fp32 [32 rows][256 B], swizzled 32B units
    __shared__ __align__(16) char Bring[3*8192];   // bf16 [64 cols][128 B], swizzled 16B units
    __shared__ float zbuf[8][32][6];
    __shared__ float cl[32][65];
    __shared__ float qres[32][3];

    // ---- addressing ----
    const int wr = t >> 2, wc = t & 3;             // wr 0..1, wc 0..3
    // A DMA source (pre-swizzled): thread covers row rA, 16B granule gA
    const int rA = t*4 + (lane >> 4);              // 0..31
    const int gA = lane & 15;                      // 16B granule in 256B row
    const int uA = gA >> 1;                        // 32B unit 0..7
    const float* asrcA = xc + (size_t)(blk*32 + rA)*2048
                       + ((uA ^ (rA & 7)) << 3) + ((gA & 1) << 2);
    // B DMA source (pre-swizzled): thread covers col colB, granule gB
    const int colB = t*8 + (lane >> 3);            // 0..63
    const int gB = lane & 7;                       // 16B granule in 128B row
    const short* bsrcB = w1bf + colB*2048 + ((gB ^ (colB & 7)) << 3);
    // fragment readers
    const int a_l  = lane >> 4;                    // 0..3
    const int arow = wr*16 + (lane & 15);          // 0..31
    const int bcol = wc*16 + (lane & 15);          // 0..63
    const int aoff0 = arow*256 + (((0*4 + a_l) ^ (arow & 7)) << 5);
    const int aoff1 = arow*256 + (((1*4 + a_l) ^ (arow & 7)) << 5);
    const int boff0 = bcol*128 + (((0*4 + a_l) ^ (bcol & 7)) << 4);
    const int boff1 = bcol*128 + (((1*4 + a_l) ^ (bcol & 7)) << 4);

    // ---- xq first (so Phase Q's wait leaves later DMAs in flight) ----
    const float* xrow = xq + (size_t)(blk*32 + (lane & 31))*6;
    float2 xq01 = *(const float2*)(xrow);
    float2 xq23 = *(const float2*)(xrow + 2);
    float2 xq45 = *(const float2*)(xrow + 4);

    // ---- prologue DMAs: chunks 0,1 into ring slots 0,1 ----
    __builtin_amdgcn_global_load_lds((gvoid_t*)(asrcA + 0*64),
        (lvoid_t*)(Aring + 0*8192 + t*1024), 16, 0, 0);
    __builtin_amdgcn_global_load_lds((gvoid_t*)(bsrcB + 0*64),
        (lvoid_t*)(Bring + 0*8192 + t*1024), 16, 0, 0);
    __builtin_amdgcn_global_load_lds((gvoid_t*)(asrcA + 1*64),
        (lvoid_t*)(Aring + 1*8192 + t*1024), 16, 0, 0);
    __builtin_amdgcn_global_load_lds((gvoid_t*)(bsrcB + 1*64),
        (lvoid_t*)(Bring + 1*8192 + t*1024), 16, 0, 0);

    // ---------- Phase Q: wave t -> U rows [t*8, t*8+8); lane&31 = batch ----------
    {
        const float xs[6] = {xq01.x, xq01.y, xq23.x, xq23.y, xq45.x, xq45.y};
        float ah[8], al[8];
        ah[0] = 1.f;
        #pragma unroll
        for (int q = 0; q < 3; ++q) {
            float c, s; __sincosf(0.5f*xs[q], &s, &c);
            const int sz = 1 << q;
            #pragma unroll
            for (int m = sz-1; m >= 0; --m) {
                float v = ah[m];
                ah[2*m+1] = v*s;
                ah[2*m+0] = v*c;
            }
        }
        al[0] = 1.f;
        #pragma unroll
        for (int q = 0; q < 3; ++q) {
            float c, s; __sincosf(0.5f*xs[3+q], &s, &c);
            const int sz = 1 << q;
            #pragma unroll
            for (int m = sz-1; m >= 0; --m) {
                float v = al[m];
                al[2*m+1] = v*s;
                al[2*m+0] = v*c;
            }
        }

        float zp[6] = {0,0,0,0,0,0};
        const float2* Urow = U + t*8*64;   // wave-uniform -> scalar loads
        for (int ii = 0; ii < 8; ++ii) {
            float rr = 0.f, ri = 0.f;
            #pragma unroll
            for (int jh = 0; jh < 8; ++jh) {
                float sr = 0.f, si = 0.f;
                #pragma unroll
                for (int jl = 0; jl < 8; ++jl) {
                    float2 u = Urow[ii*64 + jh*8 + jl];
                    sr += u.x * al[jl];
                    si += u.y * al[jl];
                }
                rr += ah[jh] * sr;
                ri += ah[jh] * si;
            }
            float p = rr*rr + ri*ri;
            int i = t*8 + ii;
            #pragma unroll
            for (int w = 0; w < 6; ++w) zp[w] += ((i >> (5-w)) & 1) ? -p : p;
        }
        if (lane < 32) {
            #pragma unroll
            for (int w = 0; w < 6; ++w) zbuf[t][lane][w] = zp[w];
        }
    }
    __syncthreads();                 // zbuf ready; drains prologue vmem (one-time)
    if (t == 0 && lane < 32) {
        float z[6];
        #pragma unroll
        for (int w = 0; w < 6; ++w) {
            float s = 0.f;
            #pragma unroll
            for (int sbi = 0; sbi < 8; ++sbi) s += zbuf[sbi][lane][w];
            z[w] = s;
        }
        #pragma unroll
        for (int j = 0; j < 3; ++j) {
            float v = ws_f[WS_CQ_F + j];
            #pragma unroll
            for (int w = 0; w < 6; ++w) v += ws_f[WS_MQ_F + j*6 + w] * z[w];
            qres[lane][j] = v;
        }
    }
    __syncthreads();                 // qres/zbuf settled; ring slots 0,1 resident

    // ---------- Phase G: 32 chunks of K=64 ----------
    floatx4 acc = {0,0,0,0};

    #pragma unroll
    for (int c = 0; c < 32; ++c) {
        const int rs = c % 3;

        // issue DMAs for chunk c+2 (slot (c+2)%3 was last read at c-1)
        if (c + 2 < 32) {
            const int wslot = (c + 2) % 3;
            __builtin_amdgcn_global_load_lds((gvoid_t*)(asrcA + (c+2)*64),
                (lvoid_t*)(Aring + wslot*8192 + t*1024), 16, 0, 0);
            __builtin_amdgcn_global_load_lds((gvoid_t*)(bsrcB + (c+2)*64),
                (lvoid_t*)(Bring + wslot*8192 + t*1024), 16, 0, 0);
        }

        // compute chunk c from ring slot rs (read-side fp32->bf16 cvt)
        const char* ab = Aring + rs*8192;
        const char* bb = Bring + rs*8192;
        float4 f00 = *(const float4*)(ab + aoff0);
        float4 f01 = *(const float4*)(ab + aoff0 + 16);
        float4 f10 = *(const float4*)(ab + aoff1);
        float4 f11 = *(const float4*)(ab + aoff1 + 16);
        short8 bv0 = *(const short8*)(bb + boff0);
        short8 bv1 = *(const short8*)(bb + boff1);
        acc = __builtin_amdgcn_mfma_f32_16x16x32_bf16(cvt_bf16x8(f00, f01), bv0, acc, 0, 0, 0);
        acc = __builtin_amdgcn_mfma_f32_16x16x32_bf16(cvt_bf16x8(f10, f11), bv1, acc, 0, 0, 0);

        // split barrier: retire this chunk's ds_reads, keep 2 DMAs flying
        if (c < 31) {
            __builtin_amdgcn_sched_barrier(0);
            asm volatile("s_waitcnt lgkmcnt(0)" ::: "memory");
            if (c <= 29) {
                asm volatile("s_waitcnt vmcnt(2)" ::: "memory");
            } else {
                asm volatile("s_waitcnt vmcnt(0)" ::: "memory");
            }
            __builtin_amdgcn_s_barrier();
            __builtin_amdgcn_sched_barrier(0);
        }
    }
    __syncthreads();                 // all ring reads done

    // epilogue: C layout col = wc*16 + (lane&15), row = wr*16 + a_l*4 + r
    const int rbase = wr*16 + a_l*4;
    const float bb1 = b1[bcol];
    #pragma unroll
    for (int r = 0; r < 4; ++r)
        cl[rbase + r][bcol] = fmaxf(acc[r] + bb1, 0.f);
    __syncthreads();

    // final head: wave j (0..2), lanes 0..31: output column j for 32 rows
    const int rr2 = lane & 31;
    if (t < 3 && lane < 32) {
        float v = 0.f;
        #pragma unroll
        for (int col = 0; col < 64; ++col) v += Wf[t*80 + col] * cl[rr2][col];
        int g = blk*32 + rr2;
        out[(size_t)g*3 + t] = v + qres[rr2][t];
    }
}

extern "C" void kernel_launch(void* const* d_in, const int* in_sizes, int n_in,
                              void* d_out, int out_size, void* d_ws, size_t ws_size,
                              hipStream_t stream) {
    const float* xc = (const float*)d_in[0];
    const float* xq = (const float*)d_in[1];
    const float* W1 = (const float*)d_in[2];
    const float* b1 = (const float*)d_in[3];
    const float* qw = (const float*)d_in[4];
    const float* Wq = (const float*)d_in[5];
    const float* bq = (const float*)d_in[6];
    const float* Wf = (const float*)d_in[7];
    const float* bf = (const float*)d_in[8];
    float* out = (float*)d_out;

    const int B = in_sizes[1] / NQ;                 // 16384
    const int n_layers = in_sizes[4] / (NQ * 3);    // 3

    char* ws = (char*)d_ws;
    float*  ws_f  = (float*)ws;
    float2* U     = (float2*)ws;
    short*  w1bf  = (short*)(ws + WS_W1BF_B);

    prep_kernel<<<dim3(321), dim3(64), 0, stream>>>(qw, n_layers, W1, Wq, bq, Wf, bf, ws_f, w1bf);
    fused_kernel<<<dim3(B/32), dim3(512), 0, stream>>>(xq, U, ws_f, xc, w1bf, b1, Wf, out);
}

// Round 11
// 225.106 us; speedup vs baseline: 1.1036x; 1.0553x over previous
//
#include <hip/hip_runtime.h>
#include <hip/hip_bf16.h>

#define NQ 6

typedef __attribute__((ext_vector_type(8))) short short8;
typedef __attribute__((ext_vector_type(4))) float floatx4;

// ---------------- ws layout (bytes) ----------------
// U_circ : float2[64*64]        @ 0        (32768 B)
// Mq     : float[18]            @ 32768
// cq     : float[3]             @ 32840
// W1bf   : short[64*2048]       @ 36864    (262144 B)
#define WS_MQ_F   8192        // float offset of Mq
#define WS_CQ_F   (8192+18)
#define WS_W1BF_B 36864

typedef const __attribute__((address_space(1))) void gvoid_t;
typedef __attribute__((address_space(3))) void lvoid_t;

// ============ K0: prep — U_circ columns, Mq/cq, W1->bf16 ============
__global__ __launch_bounds__(64) void prep_kernel(
    const float* __restrict__ qw, int n_layers,
    const float* __restrict__ W1, const float* __restrict__ Wq,
    const float* __restrict__ bq, const float* __restrict__ Wf,
    const float* __restrict__ bf, float* __restrict__ ws_f,
    short* __restrict__ w1bf)
{
    const int blk  = blockIdx.x;
    const int lane = threadIdx.x;

    if (blk == 0) {
        if (lane < 18) {
            int j = lane / 6, wi = lane % 6;
            float s = 0.f;
            for (int m = 0; m < 16; ++m) s += Wf[j*80 + 64 + m] * Wq[m*6 + wi];
            ws_f[WS_MQ_F + lane] = s;
        } else if (lane < 21) {
            int j = lane - 18;
            float s = bf[j];
            for (int m = 0; m < 16; ++m) s += Wf[j*80 + 64 + m] * bq[m];
            ws_f[WS_CQ_F + j] = s;
        }
    } else if (blk <= 64) {
        // U_circ column j: amplitudes-in-lanes, one wave
        const int j = blk - 1;
        float re = (lane == j) ? 1.f : 0.f;
        float im = 0.f;
        for (int l = 0; l < n_layers; ++l) {
            for (int w = 0; w < NQ; ++w) {
                const float* g = qw + (l*NQ + w)*3;
                float phi = g[0], th = g[1], om = g[2];
                float c, s;  __sincosf(0.5f*th, &s, &c);
                float sa, ca; __sincosf(0.5f*(phi+om), &sa, &ca);
                float sb, cb; __sincosf(0.5f*(phi-om), &sb, &cb);
                float u00r =  c*ca, u00i = -c*sa;
                float u01r = -s*cb, u01i = -s*sb;
                float u10r =  s*cb, u10i = -s*sb;
                float u11r =  c*ca, u11i =  c*sa;
                int p = 5 - w, mask = 1 << p;
                float pre = __shfl_xor(re, mask, 64);
                float pim = __shfl_xor(im, mask, 64);
                int b = (lane >> p) & 1;
                float mr = b ? u11r : u00r, mi = b ? u11i : u00i;
                float pr = b ? u10r : u01r, pi = b ? u10i : u01i;
                float nre = mr*re - mi*im + pr*pre - pi*pim;
                float nim = mr*im + mi*re + pr*pim + pi*pre;
                re = nre; im = nim;
            }
            int r = l % (NQ-1) + 1;
            for (int w = 0; w < NQ; ++w) {
                int tgt = (w + r) % NQ;
                int tmask = 1 << (5 - tgt);
                float pre = __shfl_xor(re, tmask, 64);
                float pim = __shfl_xor(im, tmask, 64);
                int cs = (lane >> (5 - w)) & 1;
                re = cs ? pre : re;
                im = cs ? pim : im;
            }
        }
        ws_f[(lane*64 + j)*2 + 0] = re;   // U[i=lane][j].re
        ws_f[(lane*64 + j)*2 + 1] = im;
    } else {
        // W1 fp32 -> bf16 (row-major [n][k]), blocks 65..320
        int idx = (blk - 65)*512 + lane*8;
        if (idx < 64*2048) {
            float4 a0 = *(const float4*)(W1 + idx);
            float4 a1 = *(const float4*)(W1 + idx + 4);
            union { short8 v; __hip_bfloat162 h[4]; } u;
            float2 f;
            f.x=a0.x; f.y=a0.y; u.h[0] = __float22bfloat162_rn(f);
            f.x=a0.z; f.y=a0.w; u.h[1] = __float22bfloat162_rn(f);
            f.x=a1.x; f.y=a1.y; u.h[2] = __float22bfloat162_rn(f);
            f.x=a1.z; f.y=a1.w; u.h[3] = __float22bfloat162_rn(f);
            *(short8*)(w1bf + idx) = u.v;
        }
    }
}

__device__ __forceinline__ short8 cvt_bf16x8(float4 a0, float4 a1) {
    union { short8 v; __hip_bfloat162 h[4]; } u;
    float2 f;
    f.x=a0.x; f.y=a0.y; u.h[0] = __float22bfloat162_rn(f);
    f.x=a0.z; f.y=a0.w; u.h[1] = __float22bfloat162_rn(f);
    f.x=a1.x; f.y=a1.y; u.h[2] = __float22bfloat162_rn(f);
    f.x=a1.z; f.y=a1.w; u.h[3] = __float22bfloat162_rn(f);
    return u.v;
}

// ============ K1: fused quantum + GEMM + ReLU + 3-wide head ============
// 512 blocks x 512 threads (8 waves, 32 rows, 2 blocks/CU). K = 32 chunks
// of 64. A: raw-fp32 global_load_lds DMA, 3-slot ring, read-side cvt.
// B: bf16 DMA, 3-slot ring. Counted vmcnt(2) split barriers.
// A swizzle: 16B granules, lds[row][g] = src[row][g ^ (row&15)]
// (full 4-bit XOR -> each 8-lane b128 phase hits 8 distinct bank clusters;
// R10's 32B-unit swizzle aliased banks -> 20.5M conflicts).
__global__ __launch_bounds__(512, 4) void fused_kernel(
    const float* __restrict__ xq, const float2* __restrict__ U,
    const float* __restrict__ ws_f,
    const float* __restrict__ xc, const short* __restrict__ w1bf,
    const float* __restrict__ b1, const float* __restrict__ Wf,
    float* __restrict__ out)
{
    const int tid  = threadIdx.x;
    const int lane = tid & 63;
    const int t    = __builtin_amdgcn_readfirstlane((int)(tid >> 6)); // wave 0..7
    const int blk  = blockIdx.x;

    __shared__ __align__(16) char Aring[3*8192];   // fp32 [32 rows][256 B], 16B-granule swizzle
    __shared__ __align__(16) char Bring[3*8192];   // bf16 [64 cols][128 B], 16B-granule swizzle
    __shared__ float zbuf[8][32][6];
    __shared__ float cl[32][65];
    __shared__ float qres[32][3];

    // ---- addressing ----
    const int wr = t >> 2, wc = t & 3;             // wr 0..1, wc 0..3
    // A DMA source (pre-swizzled, 16B granules): thread covers (row rA, granule gA)
    const int rA = t*4 + (lane >> 4);              // 0..31
    const int gA = lane & 15;                      // 0..15
    const float* asrcA = xc + (size_t)(blk*32 + rA)*2048 + ((gA ^ (rA & 15)) << 2);
    // B DMA source (pre-swizzled): thread covers col colB, granule gB
    const int colB = t*8 + (lane >> 3);            // 0..63
    const int gB = lane & 7;                       // 16B granule in 128B row
    const short* bsrcB = w1bf + colB*2048 + ((gB ^ (colB & 7)) << 3);
    // fragment readers
    const int a_l  = lane >> 4;                    // 0..3
    const int arow = wr*16 + (lane & 15);          // 0..31
    const int bcol = wc*16 + (lane & 15);          // 0..63
    const int ag0  = (2*a_l) ^ (arow & 15);        // granule of src floats [8*a_l ..+3]
    const int aoff00 = arow*256 + ( ag0      << 4);
    const int aoff01 = arow*256 + ((ag0 ^ 1) << 4);
    const int aoff10 = arow*256 + ((ag0 ^ 8) << 4);
    const int aoff11 = arow*256 + ((ag0 ^ 9) << 4);
    const int boff0 = bcol*128 + (((0*4 + a_l) ^ (bcol & 7)) << 4);
    const int boff1 = bcol*128 + (((1*4 + a_l) ^ (bcol & 7)) << 4);

    // ---- xq first (so Phase Q's wait leaves later DMAs in flight) ----
    const float* xrow = xq + (size_t)(blk*32 + (lane & 31))*6;
    float2 xq01 = *(const float2*)(xrow);
    float2 xq23 = *(const float2*)(xrow + 2);
    float2 xq45 = *(const float2*)(xrow + 4);

    // ---- prologue DMAs: chunks 0,1 into ring slots 0,1 ----
    __builtin_amdgcn_global_load_lds((gvoid_t*)(asrcA + 0*64),
        (lvoid_t*)(Aring + 0*8192 + t*1024), 16, 0, 0);
    __builtin_amdgcn_global_load_lds((gvoid_t*)(bsrcB + 0*64),
        (lvoid_t*)(Bring + 0*8192 + t*1024), 16, 0, 0);
    __builtin_amdgcn_global_load_lds((gvoid_t*)(asrcA + 1*64),
        (lvoid_t*)(Aring + 1*8192 + t*1024), 16, 0, 0);
    __builtin_amdgcn_global_load_lds((gvoid_t*)(bsrcB + 1*64),
        (lvoid_t*)(Bring + 1*8192 + t*1024), 16, 0, 0);

    // ---------- Phase Q: wave t -> U rows [t*8, t*8+8); lane&31 = batch ----------
    {
        const float xs[6] = {xq01.x, xq01.y, xq23.x, xq23.y, xq45.x, xq45.y};
        float ah[8], al[8];
        ah[0] = 1.f;
        #pragma unroll
        for (int q = 0; q < 3; ++q) {
            float c, s; __sincosf(0.5f*xs[q], &s, &c);
            const int sz = 1 << q;
            #pragma unroll
            for (int m = sz-1; m >= 0; --m) {
                float v = ah[m];
                ah[2*m+1] = v*s;
                ah[2*m+0] = v*c;
            }
        }
        al[0] = 1.f;
        #pragma unroll
        for (int q = 0; q < 3; ++q) {
            float c, s; __sincosf(0.5f*xs[3+q], &s, &c);
            const int sz = 1 << q;
            #pragma unroll
            for (int m = sz-1; m >= 0; --m) {
                float v = al[m];
                al[2*m+1] = v*s;
                al[2*m+0] = v*c;
            }
        }

        float zp[6] = {0,0,0,0,0,0};
        const float2* Urow = U + t*8*64;   // wave-uniform -> scalar loads
        for (int ii = 0; ii < 8; ++ii) {
            float rr = 0.f, ri = 0.f;
            #pragma unroll
            for (int jh = 0; jh < 8; ++jh) {
                float sr = 0.f, si = 0.f;
                #pragma unroll
                for (int jl = 0; jl < 8; ++jl) {
                    float2 u = Urow[ii*64 + jh*8 + jl];
                    sr += u.x * al[jl];
                    si += u.y * al[jl];
                }
                rr += ah[jh] * sr;
                ri += ah[jh] * si;
            }
            float p = rr*rr + ri*ri;
            int i = t*8 + ii;
            #pragma unroll
            for (int w = 0; w < 6; ++w) zp[w] += ((i >> (5-w)) & 1) ? -p : p;
        }
        if (lane < 32) {
            #pragma unroll
            for (int w = 0; w < 6; ++w) zbuf[t][lane][w] = zp[w];
        }
    }
    __syncthreads();                 // zbuf ready; drains prologue vmem (one-time)
    if (t == 0 && lane < 32) {
        float z[6];
        #pragma unroll
        for (int w = 0; w < 6; ++w) {
            float s = 0.f;
            #pragma unroll
            for (int sbi = 0; sbi < 8; ++sbi) s += zbuf[sbi][lane][w];
            z[w] = s;
        }
        #pragma unroll
        for (int j = 0; j < 3; ++j) {
            float v = ws_f[WS_CQ_F + j];
            #pragma unroll
            for (int w = 0; w < 6; ++w) v += ws_f[WS_MQ_F + j*6 + w] * z[w];
            qres[lane][j] = v;
        }
    }
    __syncthreads();                 // qres/zbuf settled; ring slots 0,1 resident

    // ---------- Phase G: 32 chunks of K=64 ----------
    floatx4 acc = {0,0,0,0};

    #pragma unroll
    for (int c = 0; c < 32; ++c) {
        const int rs = c % 3;

        // issue DMAs for chunk c+2 (slot (c+2)%3 was last read at c-1)
        if (c + 2 < 32) {
            const int wslot = (c + 2) % 3;
            __builtin_amdgcn_global_load_lds((gvoid_t*)(asrcA + (c+2)*64),
                (lvoid_t*)(Aring + wslot*8192 + t*1024), 16, 0, 0);
            __builtin_amdgcn_global_load_lds((gvoid_t*)(bsrcB + (c+2)*64),
                (lvoid_t*)(Bring + wslot*8192 + t*1024), 16, 0, 0);
        }

        // compute chunk c from ring slot rs (read-side fp32->bf16 cvt)
        const char* ab = Aring + rs*8192;
        const char* bb = Bring + rs*8192;
        float4 f00 = *(const float4*)(ab + aoff00);
        float4 f01 = *(const float4*)(ab + aoff01);
        float4 f10 = *(const float4*)(ab + aoff10);
        float4 f11 = *(const float4*)(ab + aoff11);
        short8 bv0 = *(const short8*)(bb + boff0);
        short8 bv1 = *(const short8*)(bb + boff1);
        acc = __builtin_amdgcn_mfma_f32_16x16x32_bf16(cvt_bf16x8(f00, f01), bv0, acc, 0, 0, 0);
        acc = __builtin_amdgcn_mfma_f32_16x16x32_bf16(cvt_bf16x8(f10, f11), bv1, acc, 0, 0, 0);

        // split barrier: retire this chunk's ds_reads, keep 2 DMAs flying
        if (c < 31) {
            __builtin_amdgcn_sched_barrier(0);
            asm volatile("s_waitcnt lgkmcnt(0)" ::: "memory");
            if (c <= 29) {
                asm volatile("s_waitcnt vmcnt(2)" ::: "memory");
            } else {
                asm volatile("s_waitcnt vmcnt(0)" ::: "memory");
            }
            __builtin_amdgcn_s_barrier();
            __builtin_amdgcn_sched_barrier(0);
        }
    }
    __syncthreads();                 // all ring reads done

    // epilogue: C layout col = wc*16 + (lane&15), row = wr*16 + a_l*4 + r
    const int rbase = wr*16 + a_l*4;
    const float bb1 = b1[bcol];
    #pragma unroll
    for (int r = 0; r < 4; ++r)
        cl[rbase + r][bcol] = fmaxf(acc[r] + bb1, 0.f);
    __syncthreads();

    // final head: wave j (0..2), lanes 0..31: output column j for 32 rows
    const int rr2 = lane & 31;
    if (t < 3 && lane < 32) {
        float v = 0.f;
        #pragma unroll
        for (int col = 0; col < 64; ++col) v += Wf[t*80 + col] * cl[rr2][col];
        int g = blk*32 + rr2;
        out[(size_t)g*3 + t] = v + qres[rr2][t];
    }
}

extern "C" void kernel_launch(void* const* d_in, const int* in_sizes, int n_in,
                              void* d_out, int out_size, void* d_ws, size_t ws_size,
                              hipStream_t stream) {
    const float* xc = (const float*)d_in[0];
    const float* xq = (const float*)d_in[1];
    const float* W1 = (const float*)d_in[2];
    const float* b1 = (const float*)d_in[3];
    const float* qw = (const float*)d_in[4];
    const float* Wq = (const float*)d_in[5];
    const float* bq = (const float*)d_in[6];
    const float* Wf = (const float*)d_in[7];
    const float* bf = (const float*)d_in[8];
    float* out = (float*)d_out;

    const int B = in_sizes[1] / NQ;                 // 16384
    const int n_layers = in_sizes[4] / (NQ * 3);    // 3

    char* ws = (char*)d_ws;
    float*  ws_f  = (float*)ws;
    float2* U     = (float2*)ws;
    short*  w1bf  = (short*)(ws + WS_W1BF_B);

    prep_kernel<<<dim3(321), dim3(64), 0, stream>>>(qw, n_layers, W1, Wq, bq, Wf, bf, ws_f, w1bf);
    fused_kernel<<<dim3(B/32), dim3(512), 0, stream>>>(xq, U, ws_f, xc, w1bf, b1, Wf, out);
}